// Round 9
// baseline (1530.977 us; speedup 1.0000x reference)
//
#include <hip/hip_runtime.h>
#include <math.h>

// f32 I/O, f64 accumulation everywhere (bit-exact vs np-f64 ref at f32
// materialization points — absmax 0.0 R4-R18). Workspace 96 MiB.
//
// R19: DUAL-ROLE conv — fill the f64 pipes from two sides.
// Falsified for the 28% MFMA-pipe idle: load latency (R16), block phase
// lock (R17), occupancy (R14/R15), operand pipelining (R18). The idle is
// intrinsic to the 2-wave MFMA-only schedule. R19 adds an independent
// consumer: half the blocks run the proven MFMA path (role M), half run a
// VALU-f64 path (role V, plain v_fma_f64 at the same 78.6 TF rate).
// m114: MFMA-wave + VALU-wave on one SIMD co-schedule (time ~ max).
// Role split: 1-D grid, role = (L>>8)&1 — alternating 256-block runs = one
// block/CU per fill round -> each CU gets one M + one V block co-resident.
// Per chunk both roles demand 9216 cy of f64 work -> pipes balance.
// Each output is computed by exactly one role; f64-order differences do
// not survive f32 materialization (R10 vs R12 both absmax 0.0).

constexpr int TOPK_N = 200;

typedef double f64x4 __attribute__((ext_vector_type(4)));

// ---------------------------------------------------------------------------
// L1 only (CIN=3): R10 VALU-f64 tiled fused conv+bias+relu+pool, pipelined.
// Block = 256 threads = 16x16 pooled outputs (32x32 pre-pool), CO_BLK=8.
// ---------------------------------------------------------------------------
template <int CIN, int CI_BLK, int CO_BLK>
__launch_bounds__(256)
__global__ void conv_relu_pool_pipe(const float* __restrict__ in,
                                    const float* __restrict__ wgt,
                                    const float* __restrict__ bias,
                                    float* __restrict__ out,
                                    int Hin, int Win, int Cout) {
    constexpr int SPATIAL = 34 * 34;               // 1156
    constexpr int SSLOT = (SPATIAL + 255) / 256;   // 5
    constexpr int NW = CI_BLK * 9 * CO_BLK;        // weights per chunk
    constexpr int NCHUNK = CIN / CI_BLK;
    const int Hp = Hin >> 1, Wp = Win >> 1;
    const int coChunks = Cout / CO_BLK;
    const int b  = blockIdx.z / coChunks;
    const int cz = blockIdx.z % coChunks;
    const int tid = threadIdx.x;
    const int tx = tid & 15, ty = tid >> 4;
    const int px = (blockIdx.x << 4) + tx;
    const int py = (blockIdx.y << 4) + ty;
    const int iy0 = (blockIdx.y << 5) - 1;
    const int ix0 = (blockIdx.x << 5) - 1;

    __shared__ float  s_in[2][CI_BLK * SPATIAL];
    __shared__ double s_w[2][NW];

    int soff[SSLOT];
#pragma unroll
    for (int s = 0; s < SSLOT; ++s) {
        const int cell = tid + s * 256;
        int g = -1;
        if (cell < SPATIAL) {
            const int ly = cell / 34, lx = cell - ly * 34;
            const int iy = iy0 + ly, ix = ix0 + lx;
            if ((unsigned)iy < (unsigned)Hin && (unsigned)ix < (unsigned)Win)
                g = iy * Win + ix;
        }
        soff[s] = g;
    }
    int wg = -1;
    if (tid < NW) {
        const int co   = tid & (CO_BLK - 1);
        const int rest = tid / CO_BLK;
        const int k    = rest % 9;
        const int ci   = rest / 9;
        wg = ((cz * CO_BLK + co) * CIN + ci) * 9 + k;
    }
    const size_t HW = (size_t)Hin * Win;
    const float* in_b = in + (size_t)b * CIN * HW;

    double acc[CO_BLK][4];
#pragma unroll
    for (int co = 0; co < CO_BLK; ++co)
#pragma unroll
        for (int p = 0; p < 4; ++p) acc[co][p] = 0.0;

    float rin[CI_BLK][SSLOT];
    float rw = 0.f;

#pragma unroll
    for (int ci = 0; ci < CI_BLK; ++ci) {
        const float* src = in_b + ci * HW;
#pragma unroll
        for (int s = 0; s < SSLOT; ++s) {
            const int cell = tid + s * 256;
            float v = 0.f;
            if (cell < SPATIAL) { const int g = soff[s]; if (g >= 0) v = src[g]; }
            rin[ci][s] = v;
        }
    }
    if (tid < NW) rw = wgt[wg];
#pragma unroll
    for (int ci = 0; ci < CI_BLK; ++ci)
#pragma unroll
        for (int s = 0; s < SSLOT; ++s) {
            const int cell = tid + s * 256;
            if (cell < SPATIAL) s_in[0][ci * SPATIAL + cell] = rin[ci][s];
        }
    if (tid < NW) s_w[0][tid] = (double)rw;
    __syncthreads();

    for (int c = 0; c < NCHUNK; ++c) {
        const int buf = c & 1;
        if (c + 1 < NCHUNK) {
            const int c0n = (c + 1) * CI_BLK;
#pragma unroll
            for (int ci = 0; ci < CI_BLK; ++ci) {
                const float* src = in_b + (c0n + ci) * HW;
#pragma unroll
                for (int s = 0; s < SSLOT; ++s) {
                    const int cell = tid + s * 256;
                    float v = 0.f;
                    if (cell < SPATIAL) { const int g = soff[s]; if (g >= 0) v = src[g]; }
                    rin[ci][s] = v;
                }
            }
            if (tid < NW) rw = wgt[wg + c0n * 9];
        }
#pragma unroll 1
        for (int ci = 0; ci < CI_BLK; ++ci) {
            const float* tile = &s_in[buf][ci * SPATIAL];
            double win[4][4];
#pragma unroll
            for (int iy = 0; iy < 4; ++iy) {
                float2 r0 = *(const float2*)&tile[(2 * ty + iy) * 34 + 2 * tx];
                float2 r1 = *(const float2*)&tile[(2 * ty + iy) * 34 + 2 * tx + 2];
                win[iy][0] = (double)r0.x; win[iy][1] = (double)r0.y;
                win[iy][2] = (double)r1.x; win[iy][3] = (double)r1.y;
            }
#pragma unroll
            for (int k = 0; k < 9; ++k) {
                const int ky = k / 3, kx = k % 3;
                const double* wp = &s_w[buf][(ci * 9 + k) * CO_BLK];
                double w[CO_BLK];
#pragma unroll
                for (int co = 0; co < CO_BLK; ++co) w[co] = wp[co];
#pragma unroll
                for (int p = 0; p < 4; ++p) {
                    const double v = win[(p >> 1) + ky][(p & 1) + kx];
#pragma unroll
                    for (int co = 0; co < CO_BLK; ++co)
                        acc[co][p] = fma(v, w[co], acc[co][p]);
                }
            }
        }
        if (c + 1 < NCHUNK) {
#pragma unroll
            for (int ci = 0; ci < CI_BLK; ++ci)
#pragma unroll
                for (int s = 0; s < SSLOT; ++s) {
                    const int cell = tid + s * 256;
                    if (cell < SPATIAL) s_in[buf ^ 1][ci * SPATIAL + cell] = rin[ci][s];
                }
            if (tid < NW) s_w[buf ^ 1][tid] = (double)rw;
            __syncthreads();
        }
    }

#pragma unroll
    for (int co = 0; co < CO_BLK; ++co) {
        const double bd = (double)bias[cz * CO_BLK + co];
        const float e0 = fmaxf((float)(acc[co][0] + bd), 0.f);
        const float e1 = fmaxf((float)(acc[co][1] + bd), 0.f);
        const float e2 = fmaxf((float)(acc[co][2] + bd), 0.f);
        const float e3 = fmaxf((float)(acc[co][3] + bd), 0.f);
        out[((size_t)(b * Cout + cz * CO_BLK + co) * Hp + py) * Wp + px] =
            fmaxf(fmaxf(e0, e1), fmaxf(e2, e3));
    }
}

// ---------------------------------------------------------------------------
// L2-L4: dual-role conv (R19). 1-D grid, N = gx*gy*B*coChunks blocks
// (N multiple of 512). role = (L>>8)&1; tile T = (L&255)|((L>>9)<<8).
// Tile = 32x8 pre-pool spatial x 32 couts; cob = 2*chHalf + role.
// Shared staging/LDS both roles: in f32 2x8x360 + w f64 2x8x296 = 60928 B.
// Role M: v_mfma_f64_16x16x4, layouts (CK xdlops, f64 group_size=1):
//   A l -> A[i=l&15][k=l>>4]; B l -> B[k=l>>4][j=l&15];
//   D l,r -> D[row=4r+(l>>4)][col=l&15] (REGISTER-major). Pool: vert
//   intra-thread, horiz via shfl_xor(16).
// Role V: thread = (co=tid&31, y=tid>>5); 32 f64 acc over the x-row;
//   per (ci,ky): cvt the 34-wide halo row to f64 once (broadcast LDS
//   reads), 3 kx x 32 v_fma_f64. 2304 fma x 4cy = 9216 cy/chunk = the
//   M-role's matrix demand -> pipes balance. Pool: horiz intra-thread,
//   vert via shfl_xor(32) (y-pair lanes), even-y stores float4s.
// ---------------------------------------------------------------------------
template <int CIN>
__launch_bounds__(256, 2)
__global__ void conv_dual_f64(const float* __restrict__ in,
                              const float* __restrict__ wgt,
                              const float* __restrict__ bias,
                              float* __restrict__ out,
                              int Hin, int Win, int Cout) {
    constexpr int TW = 34;               // halo tile width  (32 + 2)
    constexpr int CELLS = 34 * 10;       // halo tile cells  (8 + 2 rows)
    constexpr int CH = 360;              // padded per-ci input stride (f32)
    constexpr int CI_CHUNK = 8;
    constexpr int NCHUNK = CIN / CI_CHUNK;
    constexpr int WST = 296;             // per-ci weight stride (f64 elems)

    const int Hp = Hin >> 1, Wp = Win >> 1;
    const int coChunks = Cout >> 5;
    const int gx = Win >> 5, gy = Hin >> 3;
    const int chHalf = coChunks >> 1;

    // ---- role/tile decode (alternating 256-block runs) ----
    const int L    = (int)blockIdx.x;
    const int run  = L >> 8;
    const int role = run & 1;
    const int T    = (L & 255) | ((run >> 1) << 8);
    int t = T;
    const int bx = t % gx;  t /= gx;
    const int by = t % gy;  t /= gy;
    const int ch = t % chHalf;
    const int b  = t / chHalf;
    const int cob = (ch << 1) | role;

    const int tid = threadIdx.x;
    const int x0 = bx << 5;              // pre-pool tile origin x (32 wide)
    const int y0 = by << 3;              // pre-pool tile origin y (8 tall)

    __shared__ float  s_in[2][CI_CHUNK * CH];
    __shared__ double s_w[2][CI_CHUNK * WST];

    // ---- chunk-invariant staging geometry (shared by both roles) ----
    int soff[2];
#pragma unroll
    for (int s = 0; s < 2; ++s) {
        const int cell = tid + s * 256;
        int g = -1;
        if (cell < CELLS) {
            const int ly = cell / TW, lx = cell - ly * TW;
            const int iy = y0 - 1 + ly, ix = x0 - 1 + lx;
            if ((unsigned)iy < (unsigned)Hin && (unsigned)ix < (unsigned)Win)
                g = iy * Win + ix;
        }
        soff[s] = g;
    }
    int wgoff[9], lwoff[9];              // 2304 = 9*256 weight slots exactly
#pragma unroll
    for (int s = 0; s < 9; ++s) {
        const int idx  = s * 256 + tid;
        const int co_l = idx & 31;
        const int r    = idx >> 5;       // 0..71
        const int tap  = r % 9;
        const int ci_l = r / 9;          // 0..7
        wgoff[s] = ((cob * 32 + co_l) * CIN + ci_l) * 9 + tap;
        lwoff[s] = ci_l * WST + tap * 32 + co_l;
    }
    const size_t HW = (size_t)Hin * Win;
    const float* in_b = in + (size_t)b * CIN * HW;

    if (role == 0) {
        // =================== role M: MFMA path (R18, unchanged) ==========
        const int wv  = tid >> 6;
        const int l15 = tid & 15;
        const int l4  = (tid >> 4) & 3;
        int abase[4];
#pragma unroll
        for (int m = 0; m < 4; ++m) {
            const int dy = m >> 1, xh = m & 1;
            abase[m] = l4 * CH + (2 * wv + dy) * TW + xh * 16 + l15;
        }
        const int bbase0 = l4 * WST + l15;
        const int bbase1 = l4 * WST + 16 + l15;

        f64x4 acc[4][2];
#pragma unroll
        for (int m = 0; m < 4; ++m)
#pragma unroll
            for (int n = 0; n < 2; ++n)
#pragma unroll
                for (int j = 0; j < 4; ++j) acc[m][n][j] = 0.0;

        float rin[CI_CHUNK][2];
        float rwt[9];

#pragma unroll
        for (int ci = 0; ci < CI_CHUNK; ++ci) {
            const float* src = in_b + (size_t)ci * HW;
            rin[ci][0] = (soff[0] >= 0) ? src[soff[0]] : 0.f;
            rin[ci][1] = (soff[1] >= 0) ? src[soff[1]] : 0.f;
        }
#pragma unroll
        for (int s = 0; s < 9; ++s) rwt[s] = wgt[wgoff[s]];
#pragma unroll
        for (int ci = 0; ci < CI_CHUNK; ++ci) {
            s_in[0][ci * CH + tid] = rin[ci][0];
            if (tid < CELLS - 256) s_in[0][ci * CH + tid + 256] = rin[ci][1];
        }
#pragma unroll
        for (int s = 0; s < 9; ++s) s_w[0][lwoff[s]] = (double)rwt[s];
        __syncthreads();

#define R19_KA(kk) ((((kk)&1) * 4 * CH) + ((((kk)>>1) / 3) * TW) + (((kk)>>1) % 3))
#define R19_KB(kk) ((((kk)&1) * 4 * WST) + (((kk)>>1) * 32))
#pragma unroll 2
        for (int c = 0; c < NCHUNK; ++c) {
            const int buf = c & 1;
            if (c + 1 < NCHUNK) {
                const int c0n = (c + 1) * CI_CHUNK;
#pragma unroll
                for (int ci = 0; ci < CI_CHUNK; ++ci) {
                    const float* src = in_b + (size_t)(c0n + ci) * HW;
                    rin[ci][0] = (soff[0] >= 0) ? src[soff[0]] : 0.f;
                    rin[ci][1] = (soff[1] >= 0) ? src[soff[1]] : 0.f;
                }
#pragma unroll
                for (int s = 0; s < 9; ++s) rwt[s] = wgt[wgoff[s] + c0n * 9];
            }
            {
                const float*  ti = &s_in[buf][0];
                const double* tw = &s_w[buf][0];
                double A0, A1, A2, A3, B0, B1;
                B0 = tw[bbase0 + R19_KB(0)];
                B1 = tw[bbase1 + R19_KB(0)];
                A0 = (double)ti[abase[0] + R19_KA(0)];
                A1 = (double)ti[abase[1] + R19_KA(0)];
                A2 = (double)ti[abase[2] + R19_KA(0)];
                A3 = (double)ti[abase[3] + R19_KA(0)];
#pragma unroll
                for (int kk = 0; kk < 18; ++kk) {
                    double nA0, nA1, nA2, nA3, nB0, nB1;
                    if (kk + 1 < 18) {
                        nB0 = tw[bbase0 + R19_KB(kk + 1)];
                        nB1 = tw[bbase1 + R19_KB(kk + 1)];
                        nA0 = (double)ti[abase[0] + R19_KA(kk + 1)];
                        nA1 = (double)ti[abase[1] + R19_KA(kk + 1)];
                        nA2 = (double)ti[abase[2] + R19_KA(kk + 1)];
                        nA3 = (double)ti[abase[3] + R19_KA(kk + 1)];
                    }
                    acc[0][0] = __builtin_amdgcn_mfma_f64_16x16x4f64(A0, B0, acc[0][0], 0, 0, 0);
                    acc[0][1] = __builtin_amdgcn_mfma_f64_16x16x4f64(A0, B1, acc[0][1], 0, 0, 0);
                    acc[1][0] = __builtin_amdgcn_mfma_f64_16x16x4f64(A1, B0, acc[1][0], 0, 0, 0);
                    acc[1][1] = __builtin_amdgcn_mfma_f64_16x16x4f64(A1, B1, acc[1][1], 0, 0, 0);
                    acc[2][0] = __builtin_amdgcn_mfma_f64_16x16x4f64(A2, B0, acc[2][0], 0, 0, 0);
                    acc[2][1] = __builtin_amdgcn_mfma_f64_16x16x4f64(A2, B1, acc[2][1], 0, 0, 0);
                    acc[3][0] = __builtin_amdgcn_mfma_f64_16x16x4f64(A3, B0, acc[3][0], 0, 0, 0);
                    acc[3][1] = __builtin_amdgcn_mfma_f64_16x16x4f64(A3, B1, acc[3][1], 0, 0, 0);
                    if (kk + 1 < 18) {
                        A0 = nA0; A1 = nA1; A2 = nA2; A3 = nA3;
                        B0 = nB0; B1 = nB1;
                    }
                }
            }
            if (c + 1 < NCHUNK) {
#pragma unroll
                for (int ci = 0; ci < CI_CHUNK; ++ci) {
                    s_in[buf ^ 1][ci * CH + tid] = rin[ci][0];
                    if (tid < CELLS - 256) s_in[buf ^ 1][ci * CH + tid + 256] = rin[ci][1];
                }
#pragma unroll
                for (int s = 0; s < 9; ++s) s_w[buf ^ 1][lwoff[s]] = (double)rwt[s];
                __syncthreads();
            }
        }
#undef R19_KA
#undef R19_KB

        const int yp = (y0 >> 1) + wv;
#pragma unroll
        for (int n = 0; n < 2; ++n) {
            const int co = cob * 32 + n * 16 + l15;
            const double bd = (double)bias[co];
            float* orow = out + (((size_t)b * Cout + co) * Hp + yp) * Wp;
#pragma unroll
            for (int xh = 0; xh < 2; ++xh) {
#pragma unroll
                for (int r = 0; r < 4; ++r) {
                    const float e0 = fmaxf((float)(acc[xh][n][r]     + bd), 0.f);
                    const float e1 = fmaxf((float)(acc[2 + xh][n][r] + bd), 0.f);
                    float v = fmaxf(e0, e1);
                    const float p = __shfl_xor(v, 16, 64);
                    v = fmaxf(v, p);
                    if ((l4 & 1) == 0) {
                        const int xp = (x0 >> 1) + xh * 8 + 2 * r + (l4 >> 1);
                        orow[xp] = v;
                    }
                }
            }
        }
    } else {
        // =================== role V: VALU-f64 path =======================
        const int co = tid & 31;
        const int yy = tid >> 5;         // 0..7 (pre-pool row within tile)

        double vacc[32];
#pragma unroll
        for (int x = 0; x < 32; ++x) vacc[x] = 0.0;

        float rin[CI_CHUNK][2];
        float rwt[9];

#pragma unroll
        for (int ci = 0; ci < CI_CHUNK; ++ci) {
            const float* src = in_b + (size_t)ci * HW;
            rin[ci][0] = (soff[0] >= 0) ? src[soff[0]] : 0.f;
            rin[ci][1] = (soff[1] >= 0) ? src[soff[1]] : 0.f;
        }
#pragma unroll
        for (int s = 0; s < 9; ++s) rwt[s] = wgt[wgoff[s]];
#pragma unroll
        for (int ci = 0; ci < CI_CHUNK; ++ci) {
            s_in[0][ci * CH + tid] = rin[ci][0];
            if (tid < CELLS - 256) s_in[0][ci * CH + tid + 256] = rin[ci][1];
        }
#pragma unroll
        for (int s = 0; s < 9; ++s) s_w[0][lwoff[s]] = (double)rwt[s];
        __syncthreads();

#pragma unroll 1
        for (int c = 0; c < NCHUNK; ++c) {
            const int buf = c & 1;
            if (c + 1 < NCHUNK) {
                const int c0n = (c + 1) * CI_CHUNK;
#pragma unroll
                for (int ci = 0; ci < CI_CHUNK; ++ci) {
                    const float* src = in_b + (size_t)(c0n + ci) * HW;
                    rin[ci][0] = (soff[0] >= 0) ? src[soff[0]] : 0.f;
                    rin[ci][1] = (soff[1] >= 0) ? src[soff[1]] : 0.f;
                }
#pragma unroll
                for (int s = 0; s < 9; ++s) rwt[s] = wgt[wgoff[s] + c0n * 9];
            }
            // compute: 8 ci x (3 ky x (row cvt + 3 kx x 32 fma)) = 2304 fma
            {
                const float*  ti = &s_in[buf][0];
                const double* tw = &s_w[buf][0];
#pragma unroll 1
                for (int ci = 0; ci < CI_CHUNK; ++ci) {
                    const float*  trow = ti + ci * CH;
                    const double* wrow = tw + ci * WST;
#pragma unroll
                    for (int ky = 0; ky < 3; ++ky) {
                        double rv[34];
#pragma unroll
                        for (int xx = 0; xx < 34; ++xx)
                            rv[xx] = (double)trow[(yy + ky) * TW + xx];
#pragma unroll
                        for (int kx = 0; kx < 3; ++kx) {
                            const double w = wrow[(ky * 3 + kx) * 32 + co];
#pragma unroll
                            for (int xx = 0; xx < 32; ++xx)
                                vacc[xx] = fma(rv[xx + kx], w, vacc[xx]);
                        }
                    }
                }
            }
            if (c + 1 < NCHUNK) {
#pragma unroll
                for (int ci = 0; ci < CI_CHUNK; ++ci) {
                    s_in[buf ^ 1][ci * CH + tid] = rin[ci][0];
                    if (tid < CELLS - 256) s_in[buf ^ 1][ci * CH + tid + 256] = rin[ci][1];
                }
#pragma unroll
                for (int s = 0; s < 9; ++s) s_w[buf ^ 1][lwoff[s]] = (double)rwt[s];
                __syncthreads();
            }
        }

        // epilogue: bias -> relu -> 2x2 pool. Horizontal intra-thread;
        // vertical partner row is thread tid^32 (yy^1) -> shfl_xor(32).
        const int gco = cob * 32 + co;
        const double bd = (double)bias[gco];
        float pv[16];
#pragma unroll
        for (int k = 0; k < 16; ++k) {
            const float e0 = fmaxf((float)(vacc[2 * k]     + bd), 0.f);
            const float e1 = fmaxf((float)(vacc[2 * k + 1] + bd), 0.f);
            float p = fmaxf(e0, e1);
            const float q = __shfl_xor(p, 32, 64);
            pv[k] = fmaxf(p, q);
        }
        if ((yy & 1) == 0) {
            const int ypv = (y0 >> 1) + (yy >> 1);
            float* orow = out + (((size_t)b * Cout + gco) * Hp + ypv) * Wp + (x0 >> 1);
#pragma unroll
            for (int k = 0; k < 4; ++k) {
                float4 v4;
                v4.x = pv[4 * k];     v4.y = pv[4 * k + 1];
                v4.z = pv[4 * k + 2]; v4.w = pv[4 * k + 3];
                *(float4*)&orow[4 * k] = v4;
            }
        }
    }
}

// ---------------------------------------------------------------------------
// Head 1x1 conv (256->5, f64) + decode (f64) -> boxes/scores. 32 blocks.
// ---------------------------------------------------------------------------
__launch_bounds__(256)
__global__ void head_decode_k(const float* __restrict__ x4,
                              const float* __restrict__ wh,
                              const float* __restrict__ bh,
                              float* __restrict__ boxes,
                              float* __restrict__ scores) {
    __shared__ float s_wh[5 * 256];
    const int tid = threadIdx.x;
#pragma unroll
    for (int i = 0; i < 5; ++i) s_wh[i * 256 + tid] = wh[i * 256 + tid];
    __syncthreads();

    const int idx  = blockIdx.x * 256 + tid;  // 0..8191
    const int b    = idx >> 10;
    const int cell = idx & 1023;
    const int gy = cell >> 5, gx = cell & 31;

    double a0 = (double)bh[0], a1 = (double)bh[1], a2 = (double)bh[2],
           a3 = (double)bh[3], a4 = (double)bh[4];
    const float* xp = x4 + b * 262144 + cell;
    for (int ci = 0; ci < 256; ++ci) {
        const double v = (double)xp[ci << 10];
        a0 = fma(v, (double)s_wh[0 * 256 + ci], a0);
        a1 = fma(v, (double)s_wh[1 * 256 + ci], a1);
        a2 = fma(v, (double)s_wh[2 * 256 + ci], a2);
        a3 = fma(v, (double)s_wh[3 * 256 + ci], a3);
        a4 = fma(v, (double)s_wh[4 * 256 + ci], a4);
    }
    const double obj = 1.0 / (1.0 + exp(-a0));
    const double txs = 1.0 / (1.0 + exp(-a1));
    const double tys = 1.0 / (1.0 + exp(-a2));
    const double bw  = exp(a3) * 16.0;
    const double bhh = exp(a4) * 16.0;
    const double cx  = gx * 16.0 + txs * 16.0;
    const double cy  = gy * 16.0 + tys * 16.0;
    float* bp = boxes + idx * 4;
    bp[0] = (float)fmin(fmax(cx - bw * 0.5, 0.0), 511.0);
    bp[1] = (float)fmin(fmax(cy - bhh * 0.5, 0.0), 511.0);
    bp[2] = (float)fmin(fmax(cx + bw * 0.5, 0.0), 511.0);
    bp[3] = (float)fmin(fmax(cy + bhh * 0.5, 0.0), 511.0);
    scores[idx] = (float)obj;
}

// ---------------------------------------------------------------------------
// Per-batch top-200 (bitonic, lax.top_k tie semantics) + greedy NMS + output.
// ---------------------------------------------------------------------------
__launch_bounds__(256)
__global__ void topk_nms_k(const float* __restrict__ boxes,
                           const float* __restrict__ scores,
                           float* __restrict__ out5,
                           float* __restrict__ keep_out) {
    const int b = blockIdx.x, tid = threadIdx.x;
    __shared__ unsigned long long key[1024];
    __shared__ float bx1[TOPK_N], by1[TOPK_N], bx2[TOPK_N], by2[TOPK_N];
    __shared__ float sv[TOPK_N], ar[TOPK_N];
    __shared__ int   kp[TOPK_N];

    for (int i = tid; i < 1024; i += 256) {
        float s = scores[b * 1024 + i];
        float m = (s >= 0.01f) ? s : -1.0f;
        unsigned u = __float_as_uint(m);
        u = (u & 0x80000000u) ? ~u : (u | 0x80000000u);
        key[i] = ((unsigned long long)u << 32) | (unsigned)(1023 - i);
    }
    __syncthreads();

    for (int k = 2; k <= 1024; k <<= 1) {
        for (int j = k >> 1; j > 0; j >>= 1) {
            for (int i = tid; i < 1024; i += 256) {
                int l = i ^ j;
                if (l > i) {
                    unsigned long long a = key[i], c = key[l];
                    bool desc = ((i & k) == 0);
                    bool sw = desc ? (a < c) : (a > c);
                    if (sw) { key[i] = c; key[l] = a; }
                }
            }
            __syncthreads();
        }
    }

    for (int i = tid; i < TOPK_N; i += 256) {
        unsigned long long kk = key[i];
        unsigned u = (unsigned)(kk >> 32);
        unsigned bits = (u & 0x80000000u) ? (u & 0x7FFFFFFFu) : ~u;
        float s = __uint_as_float(bits);
        int src = 1023 - (int)(kk & 0xFFFFFFFFu);
        const float4 bb = *(const float4*)(boxes + (b * 1024 + src) * 4);
        bx1[i] = bb.x; by1[i] = bb.y; bx2[i] = bb.z; by2[i] = bb.w;
        sv[i] = s;
        ar[i] = (bb.z - bb.x) * (bb.w - bb.y);
        kp[i] = (s >= 0.01f) ? 1 : 0;
    }
    __syncthreads();

    for (int i = 0; i < TOPK_N; ++i) {
        if (kp[i]) {
            const float X1 = bx1[i], Y1 = by1[i], X2 = bx2[i], Y2 = by2[i], A = ar[i];
            for (int j = tid; j < TOPK_N; j += 256) {
                if (j > i && kp[j]) {
                    float xx1 = fmaxf(X1, bx1[j]);
                    float yy1 = fmaxf(Y1, by1[j]);
                    float xx2 = fminf(X2, bx2[j]);
                    float yy2 = fminf(Y2, by2[j]);
                    float inter = fmaxf(xx2 - xx1, 0.f) * fmaxf(yy2 - yy1, 0.f);
                    float uni = A + ar[j] - inter;
                    float iou = inter / fmaxf(uni, 1e-6f);
                    if (iou > 0.5f) kp[j] = 0;
                }
            }
        }
        __syncthreads();
    }

    for (int i = tid; i < TOPK_N; i += 256) {
        float kf = kp[i] ? 1.f : 0.f;
        float s  = sv[i];
        float sc = (s >= 0.01f) ? s : 0.f;
        float* op = out5 + (b * TOPK_N + i) * 5;
        op[0] = bx1[i] * kf;
        op[1] = by1[i] * kf;
        op[2] = bx2[i] * kf;
        op[3] = by2[i] * kf;
        op[4] = sc * kf;
        keep_out[b * TOPK_N + i] = kf;
    }
}

extern "C" void kernel_launch(void* const* d_in, const int* in_sizes, int n_in,
                              void* d_out, int out_size, void* d_ws, size_t ws_size,
                              hipStream_t stream) {
    const float* images = (const float*)d_in[0];
    const float* w1 = (const float*)d_in[1];
    const float* b1 = (const float*)d_in[2];
    const float* w2 = (const float*)d_in[3];
    const float* b2 = (const float*)d_in[4];
    const float* w3 = (const float*)d_in[5];
    const float* b3 = (const float*)d_in[6];
    const float* w4 = (const float*)d_in[7];
    const float* b4 = (const float*)d_in[8];
    const float* wh = (const float*)d_in[9];
    const float* bh = (const float*)d_in[10];
    float* out = (float*)d_out;

    float* A    = (float*)d_ws;          // x1 [8,32,256,256] -> x3 [8,128,64,64]
    float* Bbuf = A + 16777216;          // x2 [8,64,128,128] -> x4 [8,256,32,32]
    float* boxes  = A + 8388608;         // dead x1 space: 32768 floats
    float* scores = A + 8388608 + 32768; //  8192 floats

    // L1: 3->32, 512x512 -> 256x256. VALU-f64 template (CIN=3 not mfma-shaped).
    conv_relu_pool_pipe<3, 3, 8><<<dim3(16, 16, 8 * 4), 256, 0, stream>>>(
        images, w1, b1, A, 512, 512, 32);
    // L2: 32->64, 256x256 in. Dual-role 1-D grid: N = 8*32*8*2 = 4096.
    conv_dual_f64<32><<<dim3(4096), 256, 0, stream>>>(
        A, w2, b2, Bbuf, 256, 256, 64);
    // L3: 64->128, 128x128 in. N = 4*16*8*4 = 2048.
    conv_dual_f64<64><<<dim3(2048), 256, 0, stream>>>(
        Bbuf, w3, b3, A, 128, 128, 128);
    // L4: 128->256, 64x64 in. N = 2*8*8*8 = 1024.
    conv_dual_f64<128><<<dim3(1024), 256, 0, stream>>>(
        A, w4, b4, Bbuf, 64, 64, 256);
    // Head + decode: 32 blocks, coalesced
    head_decode_k<<<32, 256, 0, stream>>>(Bbuf, wh, bh, boxes, scores);
    // Top-k + NMS + output
    topk_nms_k<<<8, 256, 0, stream>>>(boxes, scores, out, out + 8 * TOPK_N * 5);
}

// Round 10
// 1360.435 us; speedup vs baseline: 1.1254x; 1.1254x over previous
//
#include <hip/hip_runtime.h>
#include <math.h>

// f32 I/O, f64 accumulation everywhere (bit-exact vs np-f64 ref at f32
// materialization points — absmax 0.0 R4-R18). Workspace 96 MiB.
//
// R20 = R18 structure with CI_CHUNK=16 (half the barrier rounds).
// R19 post-mortem: dual-role FAILED — v_fma_f64 vector rate is ~half the
// matrix rate (V blocks 2x slower; layer = max(roles) = 477µs). Reverted.
// Falsified for the ~28% matrix-pipe idle: load latency (R16), block
// phase-lock (R17), occupancy (R14/R15), operand pipelining (R18), dual
// pipe (R19). Surviving model: a ~9K-cy PER-ROUND serial window (commit +
// barrier drain; nearly wave-count-invariant: 6.8K @1 wave, 8.9K @2).
// R20 amortizes it: 16-ci chunks -> 288 mfma/wave/round (36.9K cy busy per
// 2-wave round vs same ~9K gap) -> predicted util 67% -> ~81%.
// Weights f32 in LDS (cvt in compute, free at 12% VALUBusy). CH=344
// (=24 mod 32: k-groups at banks {0,24,16,8}, 2 lanes/bank = free),
// WST=296 (=8 mod 32). LDS = 44032 + 37888 = 81920 B exactly -> 2
// blocks/CU = the full 160 KiB. Accumulation order preserved EXACTLY:
// compute = 2 sub-chunks of 8 ci, each the verbatim R18 18-iter pipeline
// -> per-acc (tap,ci) sequence identical to R13 -> absmax 0.0.

constexpr int TOPK_N = 200;

typedef double f64x4 __attribute__((ext_vector_type(4)));

// ---------------------------------------------------------------------------
// L1 only (CIN=3): R10 VALU-f64 tiled fused conv+bias+relu+pool, pipelined.
// Block = 256 threads = 16x16 pooled outputs (32x32 pre-pool), CO_BLK=8.
// ---------------------------------------------------------------------------
template <int CIN, int CI_BLK, int CO_BLK>
__launch_bounds__(256)
__global__ void conv_relu_pool_pipe(const float* __restrict__ in,
                                    const float* __restrict__ wgt,
                                    const float* __restrict__ bias,
                                    float* __restrict__ out,
                                    int Hin, int Win, int Cout) {
    constexpr int SPATIAL = 34 * 34;               // 1156
    constexpr int SSLOT = (SPATIAL + 255) / 256;   // 5
    constexpr int NW = CI_BLK * 9 * CO_BLK;        // weights per chunk
    constexpr int NCHUNK = CIN / CI_BLK;
    const int Hp = Hin >> 1, Wp = Win >> 1;
    const int coChunks = Cout / CO_BLK;
    const int b  = blockIdx.z / coChunks;
    const int cz = blockIdx.z % coChunks;
    const int tid = threadIdx.x;
    const int tx = tid & 15, ty = tid >> 4;
    const int px = (blockIdx.x << 4) + tx;
    const int py = (blockIdx.y << 4) + ty;
    const int iy0 = (blockIdx.y << 5) - 1;
    const int ix0 = (blockIdx.x << 5) - 1;

    __shared__ float  s_in[2][CI_BLK * SPATIAL];
    __shared__ double s_w[2][NW];

    int soff[SSLOT];
#pragma unroll
    for (int s = 0; s < SSLOT; ++s) {
        const int cell = tid + s * 256;
        int g = -1;
        if (cell < SPATIAL) {
            const int ly = cell / 34, lx = cell - ly * 34;
            const int iy = iy0 + ly, ix = ix0 + lx;
            if ((unsigned)iy < (unsigned)Hin && (unsigned)ix < (unsigned)Win)
                g = iy * Win + ix;
        }
        soff[s] = g;
    }
    int wg = -1;
    if (tid < NW) {
        const int co   = tid & (CO_BLK - 1);
        const int rest = tid / CO_BLK;
        const int k    = rest % 9;
        const int ci   = rest / 9;
        wg = ((cz * CO_BLK + co) * CIN + ci) * 9 + k;
    }
    const size_t HW = (size_t)Hin * Win;
    const float* in_b = in + (size_t)b * CIN * HW;

    double acc[CO_BLK][4];
#pragma unroll
    for (int co = 0; co < CO_BLK; ++co)
#pragma unroll
        for (int p = 0; p < 4; ++p) acc[co][p] = 0.0;

    float rin[CI_BLK][SSLOT];
    float rw = 0.f;

#pragma unroll
    for (int ci = 0; ci < CI_BLK; ++ci) {
        const float* src = in_b + ci * HW;
#pragma unroll
        for (int s = 0; s < SSLOT; ++s) {
            const int cell = tid + s * 256;
            float v = 0.f;
            if (cell < SPATIAL) { const int g = soff[s]; if (g >= 0) v = src[g]; }
            rin[ci][s] = v;
        }
    }
    if (tid < NW) rw = wgt[wg];
#pragma unroll
    for (int ci = 0; ci < CI_BLK; ++ci)
#pragma unroll
        for (int s = 0; s < SSLOT; ++s) {
            const int cell = tid + s * 256;
            if (cell < SPATIAL) s_in[0][ci * SPATIAL + cell] = rin[ci][s];
        }
    if (tid < NW) s_w[0][tid] = (double)rw;
    __syncthreads();

    for (int c = 0; c < NCHUNK; ++c) {
        const int buf = c & 1;
        if (c + 1 < NCHUNK) {
            const int c0n = (c + 1) * CI_BLK;
#pragma unroll
            for (int ci = 0; ci < CI_BLK; ++ci) {
                const float* src = in_b + (c0n + ci) * HW;
#pragma unroll
                for (int s = 0; s < SSLOT; ++s) {
                    const int cell = tid + s * 256;
                    float v = 0.f;
                    if (cell < SPATIAL) { const int g = soff[s]; if (g >= 0) v = src[g]; }
                    rin[ci][s] = v;
                }
            }
            if (tid < NW) rw = wgt[wg + c0n * 9];
        }
#pragma unroll 1
        for (int ci = 0; ci < CI_BLK; ++ci) {
            const float* tile = &s_in[buf][ci * SPATIAL];
            double win[4][4];
#pragma unroll
            for (int iy = 0; iy < 4; ++iy) {
                float2 r0 = *(const float2*)&tile[(2 * ty + iy) * 34 + 2 * tx];
                float2 r1 = *(const float2*)&tile[(2 * ty + iy) * 34 + 2 * tx + 2];
                win[iy][0] = (double)r0.x; win[iy][1] = (double)r0.y;
                win[iy][2] = (double)r1.x; win[iy][3] = (double)r1.y;
            }
#pragma unroll
            for (int k = 0; k < 9; ++k) {
                const int ky = k / 3, kx = k % 3;
                const double* wp = &s_w[buf][(ci * 9 + k) * CO_BLK];
                double w[CO_BLK];
#pragma unroll
                for (int co = 0; co < CO_BLK; ++co) w[co] = wp[co];
#pragma unroll
                for (int p = 0; p < 4; ++p) {
                    const double v = win[(p >> 1) + ky][(p & 1) + kx];
#pragma unroll
                    for (int co = 0; co < CO_BLK; ++co)
                        acc[co][p] = fma(v, w[co], acc[co][p]);
                }
            }
        }
        if (c + 1 < NCHUNK) {
#pragma unroll
            for (int ci = 0; ci < CI_BLK; ++ci)
#pragma unroll
                for (int s = 0; s < SSLOT; ++s) {
                    const int cell = tid + s * 256;
                    if (cell < SPATIAL) s_in[buf ^ 1][ci * SPATIAL + cell] = rin[ci][s];
                }
            if (tid < NW) s_w[buf ^ 1][tid] = (double)rw;
            __syncthreads();
        }
    }

#pragma unroll
    for (int co = 0; co < CO_BLK; ++co) {
        const double bd = (double)bias[cz * CO_BLK + co];
        const float e0 = fmaxf((float)(acc[co][0] + bd), 0.f);
        const float e1 = fmaxf((float)(acc[co][1] + bd), 0.f);
        const float e2 = fmaxf((float)(acc[co][2] + bd), 0.f);
        const float e3 = fmaxf((float)(acc[co][3] + bd), 0.f);
        out[((size_t)(b * Cout + cz * CO_BLK + co) * Hp + py) * Wp + px] =
            fmaxf(fmaxf(e0, e1), fmaxf(e2, e3));
    }
}

// ---------------------------------------------------------------------------
// L2-L4: implicit-GEMM conv via v_mfma_f64_16x16x4 (R20: 16-ci rounds).
// Block = 256 thr = 4 waves; tile = 32x8 pre-pool spatial x 32 cout.
// Layouts (CK xdlops, f64 group_size=1):
//   A lane l -> A[i=l&15][k=l>>4];  B lane l -> B[k=l>>4][j=l&15];
//   D lane l reg r -> D[row = 4*r + (l>>4)][col = l&15]   (REGISTER-major)
// Pooling: vertical intra-thread (m pairs), horizontal via __shfl_xor(16).
// LDS: in f32 2x16x344 + w f32 2x16x296 = 81920 B exactly (2 blocks/CU).
// Compute per round: 2 sub-chunks (h) x R18's 18-iter pipelined loop.
// ---------------------------------------------------------------------------
template <int CIN>
__launch_bounds__(256, 2)
__global__ void conv_mfma_f64(const float* __restrict__ in,
                              const float* __restrict__ wgt,
                              const float* __restrict__ bias,
                              float* __restrict__ out,
                              int Hin, int Win, int Cout) {
    constexpr int TW = 34;               // halo tile width  (32 + 2)
    constexpr int CELLS = 34 * 10;       // halo tile cells  (8 + 2 rows)
    constexpr int CH = 344;              // per-ci input stride (f32, ==24 mod 32)
    constexpr int CI_CHUNK = 16;
    constexpr int NCHUNK = CIN / CI_CHUNK;
    constexpr int WST = 296;             // per-ci weight stride (f32, ==8 mod 32)
    constexpr int NWS = CI_CHUNK * 9 * 32 / 256;   // 18 weight slots

    const int Hp = Hin >> 1, Wp = Win >> 1;
    const int coChunks = Cout >> 5;
    const int b   = blockIdx.z / coChunks;
    const int cob = blockIdx.z % coChunks;
    const int tid = threadIdx.x;
    const int wv  = tid >> 6;
    const int l15 = tid & 15;
    const int l4  = (tid >> 4) & 3;
    const int x0 = blockIdx.x << 5;      // pre-pool tile origin x (32 wide)
    const int y0 = blockIdx.y << 3;      // pre-pool tile origin y (8 tall)

    __shared__ float s_in[2][CI_CHUNK * CH];
    __shared__ float s_w[2][CI_CHUNK * WST];

    // ---- chunk-invariant staging geometry ----
    int soff[2];
#pragma unroll
    for (int s = 0; s < 2; ++s) {
        const int cell = tid + s * 256;
        int g = -1;
        if (cell < CELLS) {
            const int ly = cell / TW, lx = cell - ly * TW;
            const int iy = y0 - 1 + ly, ix = x0 - 1 + lx;
            if ((unsigned)iy < (unsigned)Hin && (unsigned)ix < (unsigned)Win)
                g = iy * Win + ix;
        }
        soff[s] = g;
    }
    // Weight slots: idx = s*256+tid (s<18) covers the 4608 chunk weights.
    // co_l = tid&31; r = s*8 + (tid>>5) in 0..143; tap = r%9, ci = r/9.
    const int co_l = tid & 31;
    const int r8   = tid >> 5;
    const int wbase = (cob * 32 + co_l) * CIN * 9;

    const size_t HW = (size_t)Hin * Win;
    const float* in_b = in + (size_t)b * CIN * HW;

    // ---- per-wave mfma read bases (f32 element indices) ----
    int abase[4];
#pragma unroll
    for (int m = 0; m < 4; ++m) {
        const int dy = m >> 1, xh = m & 1;
        abase[m] = l4 * CH + (2 * wv + dy) * TW + xh * 16 + l15;
    }
    const int bbase0 = l4 * WST + l15;
    const int bbase1 = l4 * WST + 16 + l15;

    f64x4 acc[4][2];
#pragma unroll
    for (int m = 0; m < 4; ++m)
#pragma unroll
        for (int n = 0; n < 2; ++n)
#pragma unroll
            for (int j = 0; j < 4; ++j) acc[m][n][j] = 0.0;

    float rin[CI_CHUNK][2];
    float rwt[NWS];

    // ---- prologue: fetch + commit chunk 0 ----
#pragma unroll
    for (int ci = 0; ci < CI_CHUNK; ++ci) {
        const float* src = in_b + (size_t)ci * HW;
        rin[ci][0] = (soff[0] >= 0) ? src[soff[0]] : 0.f;
        rin[ci][1] = (soff[1] >= 0) ? src[soff[1]] : 0.f;
    }
#pragma unroll
    for (int s = 0; s < NWS; ++s) {
        const int r = s * 8 + r8;
        const int tap = r % 9, ci = r / 9;
        rwt[s] = wgt[wbase + ci * 9 + tap];
    }
#pragma unroll
    for (int ci = 0; ci < CI_CHUNK; ++ci) {
        s_in[0][ci * CH + tid] = rin[ci][0];
        if (tid < CELLS - 256) s_in[0][ci * CH + tid + 256] = rin[ci][1];
    }
#pragma unroll
    for (int s = 0; s < NWS; ++s) {
        const int r = s * 8 + r8;
        const int tap = r % 9, ci = r / 9;
        s_w[0][ci * WST + tap * 32 + co_l] = rwt[s];
    }
    __syncthreads();

    // kk = tap*2 + g within a sub-chunk h (ci4-group = 2h + g).
#define R20_KA(kk) ((((kk)&1) * 4 * CH) + ((((kk)>>1) / 3) * TW) + (((kk)>>1) % 3))
#define R20_KB(kk) ((((kk)&1) * 4 * WST) + (((kk)>>1) * 32))

#pragma unroll 1
    for (int c = 0; c < NCHUNK; ++c) {
        const int buf = c & 1;
        // ---- issue next round's global loads (land under the mfmas) ----
        if (c + 1 < NCHUNK) {
            const int c0n = (c + 1) * CI_CHUNK;
#pragma unroll
            for (int ci = 0; ci < CI_CHUNK; ++ci) {
                const float* src = in_b + (size_t)(c0n + ci) * HW;
                rin[ci][0] = (soff[0] >= 0) ? src[soff[0]] : 0.f;
                rin[ci][1] = (soff[1] >= 0) ? src[soff[1]] : 0.f;
            }
#pragma unroll
            for (int s = 0; s < NWS; ++s) {
                const int r = s * 8 + r8;
                const int tap = r % 9, ci = r / 9;
                rwt[s] = wgt[wbase + (c0n + ci) * 9 + tap];
            }
        }
        // ---- compute: 2 sub-chunks x 18 kk-iters x 8 mfma = 288 mfma ----
#pragma unroll
        for (int h = 0; h < 2; ++h) {
            const float* ti = &s_in[buf][h * 8 * CH];
            const float* tw = &s_w[buf][h * 8 * WST];
            double A0, A1, A2, A3, B0, B1;
            B0 = (double)tw[bbase0 + R20_KB(0)];
            B1 = (double)tw[bbase1 + R20_KB(0)];
            A0 = (double)ti[abase[0] + R20_KA(0)];
            A1 = (double)ti[abase[1] + R20_KA(0)];
            A2 = (double)ti[abase[2] + R20_KA(0)];
            A3 = (double)ti[abase[3] + R20_KA(0)];
#pragma unroll
            for (int kk = 0; kk < 18; ++kk) {
                double nA0, nA1, nA2, nA3, nB0, nB1;
                if (kk + 1 < 18) {
                    nB0 = (double)tw[bbase0 + R20_KB(kk + 1)];
                    nB1 = (double)tw[bbase1 + R20_KB(kk + 1)];
                    nA0 = (double)ti[abase[0] + R20_KA(kk + 1)];
                    nA1 = (double)ti[abase[1] + R20_KA(kk + 1)];
                    nA2 = (double)ti[abase[2] + R20_KA(kk + 1)];
                    nA3 = (double)ti[abase[3] + R20_KA(kk + 1)];
                }
                acc[0][0] = __builtin_amdgcn_mfma_f64_16x16x4f64(A0, B0, acc[0][0], 0, 0, 0);
                acc[0][1] = __builtin_amdgcn_mfma_f64_16x16x4f64(A0, B1, acc[0][1], 0, 0, 0);
                acc[1][0] = __builtin_amdgcn_mfma_f64_16x16x4f64(A1, B0, acc[1][0], 0, 0, 0);
                acc[1][1] = __builtin_amdgcn_mfma_f64_16x16x4f64(A1, B1, acc[1][1], 0, 0, 0);
                acc[2][0] = __builtin_amdgcn_mfma_f64_16x16x4f64(A2, B0, acc[2][0], 0, 0, 0);
                acc[2][1] = __builtin_amdgcn_mfma_f64_16x16x4f64(A2, B1, acc[2][1], 0, 0, 0);
                acc[3][0] = __builtin_amdgcn_mfma_f64_16x16x4f64(A3, B0, acc[3][0], 0, 0, 0);
                acc[3][1] = __builtin_amdgcn_mfma_f64_16x16x4f64(A3, B1, acc[3][1], 0, 0, 0);
                if (kk + 1 < 18) {
                    A0 = nA0; A1 = nA1; A2 = nA2; A3 = nA3;
                    B0 = nB0; B1 = nB1;
                }
            }
        }
        // ---- commit prefetched regs to the other buffer, one barrier ----
        if (c + 1 < NCHUNK) {
#pragma unroll
            for (int ci = 0; ci < CI_CHUNK; ++ci) {
                s_in[buf ^ 1][ci * CH + tid] = rin[ci][0];
                if (tid < CELLS - 256) s_in[buf ^ 1][ci * CH + tid + 256] = rin[ci][1];
            }
#pragma unroll
            for (int s = 0; s < NWS; ++s) {
                const int r = s * 8 + r8;
                const int tap = r % 9, ci = r / 9;
                s_w[buf ^ 1][ci * WST + tap * 32 + co_l] = rwt[s];
            }
            __syncthreads();
        }
    }
#undef R20_KA
#undef R20_KB

    // ---- epilogue: bias (f64) -> relu (f32) -> 2x2 maxpool -> store.
    // Reg r of acc[m][n] holds pre-pool x = x0 + xh*16 + 4r + l4, y = y0+2wv+dy.
    // Vertical pool intra-thread (m pairs); horizontal partner x^1 = lane^16.
    const int yp = (y0 >> 1) + wv;
#pragma unroll
    for (int n = 0; n < 2; ++n) {
        const int co = cob * 32 + n * 16 + l15;
        const double bd = (double)bias[co];
        float* orow = out + (((size_t)b * Cout + co) * Hp + yp) * Wp;
#pragma unroll
        for (int xh = 0; xh < 2; ++xh) {
#pragma unroll
            for (int r = 0; r < 4; ++r) {
                const float e0 = fmaxf((float)(acc[xh][n][r]     + bd), 0.f);
                const float e1 = fmaxf((float)(acc[2 + xh][n][r] + bd), 0.f);
                float v = fmaxf(e0, e1);                 // vertical pool
                const float p = __shfl_xor(v, 16, 64);   // horizontal partner
                v = fmaxf(v, p);
                if ((l4 & 1) == 0) {
                    const int xp = (x0 >> 1) + xh * 8 + 2 * r + (l4 >> 1);
                    orow[xp] = v;
                }
            }
        }
    }
}

// ---------------------------------------------------------------------------
// Head 1x1 conv (256->5, f64) + decode (f64) -> boxes/scores. 32 blocks.
// ---------------------------------------------------------------------------
__launch_bounds__(256)
__global__ void head_decode_k(const float* __restrict__ x4,
                              const float* __restrict__ wh,
                              const float* __restrict__ bh,
                              float* __restrict__ boxes,
                              float* __restrict__ scores) {
    __shared__ float s_wh[5 * 256];
    const int tid = threadIdx.x;
#pragma unroll
    for (int i = 0; i < 5; ++i) s_wh[i * 256 + tid] = wh[i * 256 + tid];
    __syncthreads();

    const int idx  = blockIdx.x * 256 + tid;  // 0..8191
    const int b    = idx >> 10;
    const int cell = idx & 1023;
    const int gy = cell >> 5, gx = cell & 31;

    double a0 = (double)bh[0], a1 = (double)bh[1], a2 = (double)bh[2],
           a3 = (double)bh[3], a4 = (double)bh[4];
    const float* xp = x4 + b * 262144 + cell;
    for (int ci = 0; ci < 256; ++ci) {
        const double v = (double)xp[ci << 10];
        a0 = fma(v, (double)s_wh[0 * 256 + ci], a0);
        a1 = fma(v, (double)s_wh[1 * 256 + ci], a1);
        a2 = fma(v, (double)s_wh[2 * 256 + ci], a2);
        a3 = fma(v, (double)s_wh[3 * 256 + ci], a3);
        a4 = fma(v, (double)s_wh[4 * 256 + ci], a4);
    }
    const double obj = 1.0 / (1.0 + exp(-a0));
    const double txs = 1.0 / (1.0 + exp(-a1));
    const double tys = 1.0 / (1.0 + exp(-a2));
    const double bw  = exp(a3) * 16.0;
    const double bhh = exp(a4) * 16.0;
    const double cx  = gx * 16.0 + txs * 16.0;
    const double cy  = gy * 16.0 + tys * 16.0;
    float* bp = boxes + idx * 4;
    bp[0] = (float)fmin(fmax(cx - bw * 0.5, 0.0), 511.0);
    bp[1] = (float)fmin(fmax(cy - bhh * 0.5, 0.0), 511.0);
    bp[2] = (float)fmin(fmax(cx + bw * 0.5, 0.0), 511.0);
    bp[3] = (float)fmin(fmax(cy + bhh * 0.5, 0.0), 511.0);
    scores[idx] = (float)obj;
}

// ---------------------------------------------------------------------------
// Per-batch top-200 (bitonic, lax.top_k tie semantics) + greedy NMS + output.
// ---------------------------------------------------------------------------
__launch_bounds__(256)
__global__ void topk_nms_k(const float* __restrict__ boxes,
                           const float* __restrict__ scores,
                           float* __restrict__ out5,
                           float* __restrict__ keep_out) {
    const int b = blockIdx.x, tid = threadIdx.x;
    __shared__ unsigned long long key[1024];
    __shared__ float bx1[TOPK_N], by1[TOPK_N], bx2[TOPK_N], by2[TOPK_N];
    __shared__ float sv[TOPK_N], ar[TOPK_N];
    __shared__ int   kp[TOPK_N];

    for (int i = tid; i < 1024; i += 256) {
        float s = scores[b * 1024 + i];
        float m = (s >= 0.01f) ? s : -1.0f;
        unsigned u = __float_as_uint(m);
        u = (u & 0x80000000u) ? ~u : (u | 0x80000000u);
        key[i] = ((unsigned long long)u << 32) | (unsigned)(1023 - i);
    }
    __syncthreads();

    for (int k = 2; k <= 1024; k <<= 1) {
        for (int j = k >> 1; j > 0; j >>= 1) {
            for (int i = tid; i < 1024; i += 256) {
                int l = i ^ j;
                if (l > i) {
                    unsigned long long a = key[i], c = key[l];
                    bool desc = ((i & k) == 0);
                    bool sw = desc ? (a < c) : (a > c);
                    if (sw) { key[i] = c; key[l] = a; }
                }
            }
            __syncthreads();
        }
    }

    for (int i = tid; i < TOPK_N; i += 256) {
        unsigned long long kk = key[i];
        unsigned u = (unsigned)(kk >> 32);
        unsigned bits = (u & 0x80000000u) ? (u & 0x7FFFFFFFu) : ~u;
        float s = __uint_as_float(bits);
        int src = 1023 - (int)(kk & 0xFFFFFFFFu);
        const float4 bb = *(const float4*)(boxes + (b * 1024 + src) * 4);
        bx1[i] = bb.x; by1[i] = bb.y; bx2[i] = bb.z; by2[i] = bb.w;
        sv[i] = s;
        ar[i] = (bb.z - bb.x) * (bb.w - bb.y);
        kp[i] = (s >= 0.01f) ? 1 : 0;
    }
    __syncthreads();

    for (int i = 0; i < TOPK_N; ++i) {
        if (kp[i]) {
            const float X1 = bx1[i], Y1 = by1[i], X2 = bx2[i], Y2 = by2[i], A = ar[i];
            for (int j = tid; j < TOPK_N; j += 256) {
                if (j > i && kp[j]) {
                    float xx1 = fmaxf(X1, bx1[j]);
                    float yy1 = fmaxf(Y1, by1[j]);
                    float xx2 = fminf(X2, bx2[j]);
                    float yy2 = fminf(Y2, by2[j]);
                    float inter = fmaxf(xx2 - xx1, 0.f) * fmaxf(yy2 - yy1, 0.f);
                    float uni = A + ar[j] - inter;
                    float iou = inter / fmaxf(uni, 1e-6f);
                    if (iou > 0.5f) kp[j] = 0;
                }
            }
        }
        __syncthreads();
    }

    for (int i = tid; i < TOPK_N; i += 256) {
        float kf = kp[i] ? 1.f : 0.f;
        float s  = sv[i];
        float sc = (s >= 0.01f) ? s : 0.f;
        float* op = out5 + (b * TOPK_N + i) * 5;
        op[0] = bx1[i] * kf;
        op[1] = by1[i] * kf;
        op[2] = bx2[i] * kf;
        op[3] = by2[i] * kf;
        op[4] = sc * kf;
        keep_out[b * TOPK_N + i] = kf;
    }
}

extern "C" void kernel_launch(void* const* d_in, const int* in_sizes, int n_in,
                              void* d_out, int out_size, void* d_ws, size_t ws_size,
                              hipStream_t stream) {
    const float* images = (const float*)d_in[0];
    const float* w1 = (const float*)d_in[1];
    const float* b1 = (const float*)d_in[2];
    const float* w2 = (const float*)d_in[3];
    const float* b2 = (const float*)d_in[4];
    const float* w3 = (const float*)d_in[5];
    const float* b3 = (const float*)d_in[6];
    const float* w4 = (const float*)d_in[7];
    const float* b4 = (const float*)d_in[8];
    const float* wh = (const float*)d_in[9];
    const float* bh = (const float*)d_in[10];
    float* out = (float*)d_out;

    float* A    = (float*)d_ws;          // x1 [8,32,256,256] -> x3 [8,128,64,64]
    float* Bbuf = A + 16777216;          // x2 [8,64,128,128] -> x4 [8,256,32,32]
    float* boxes  = A + 8388608;         // dead x1 space: 32768 floats
    float* scores = A + 8388608 + 32768; //  8192 floats

    // L1: 3->32, 512x512 -> 256x256. VALU-f64 template (CIN=3 not mfma-shaped).
    conv_relu_pool_pipe<3, 3, 8><<<dim3(16, 16, 8 * 4), 256, 0, stream>>>(
        images, w1, b1, A, 512, 512, 32);
    // L2: 32->64, 256x256 in. MFMA-f64: grid (Wpre/32, Hpre/8, B*Cout/32).
    conv_mfma_f64<32><<<dim3(8, 32, 8 * 2), 256, 0, stream>>>(
        A, w2, b2, Bbuf, 256, 256, 64);
    // L3: 64->128, 128x128 in.
    conv_mfma_f64<64><<<dim3(4, 16, 8 * 4), 256, 0, stream>>>(
        Bbuf, w3, b3, A, 128, 128, 128);
    // L4: 128->256, 64x64 in.
    conv_mfma_f64<128><<<dim3(2, 8, 8 * 8), 256, 0, stream>>>(
        A, w4, b4, Bbuf, 64, 64, 256);
    // Head + decode: 32 blocks, coalesced
    head_decode_k<<<32, 256, 0, stream>>>(Bbuf, wh, bh, boxes, scores);
    // Top-k + NMS + output
    topk_nms_k<<<8, 256, 0, stream>>>(boxes, scores, out, out + 8 * TOPK_N * 5);
}

// Round 11
// 1308.724 us; speedup vs baseline: 1.1698x; 1.0395x over previous
//
#include <hip/hip_runtime.h>
#include <math.h>

// f32 I/O, f64 accumulation everywhere (bit-exact vs np-f64 ref at f32
// materialization points — absmax 0.0 R4-R18, R20). Workspace 96 MiB.
//
// R21: CLEAN test of the per-round-overhead model (R20 was confounded by
// spills: rin[16][2]+rwt[18] live across 37K cy -> WRITE 94MB, 418µs).
// R21 removes the input registers entirely: global_load_lds staging
// (R16 mechanics, proven correct, -2%) + CI_CHUNK=16 (half the rounds).
// Only rwt[18] survives (weights need a [co][ci][tap]->[ci][tap][co]
// transpose that gload_lds cannot do). If the ~9K-cy/round overhead is
// fixed, halving rounds -> 364 -> ~310-320 µs/layer; if neutral, the
// structure is at its effective-mfma-throughput roofline (~95cy/inst).
// CH=344 (==24 mod 32: A k-groups at banks {0,24,16,8}, 2-way = free),
// WST=296 f32 (==8). LDS = 44032+37888 = 81920 B exactly (2 blocks/CU).
// Compute = 2 sub-chunks x verbatim R18 18-iter pipeline -> per-acc
// (tap,ci) order bit-identical to R13 -> absmax 0.0.

constexpr int TOPK_N = 200;

typedef double f64x4 __attribute__((ext_vector_type(4)));

// ---------------------------------------------------------------------------
// L1 only (CIN=3): R10 VALU-f64 tiled fused conv+bias+relu+pool, pipelined.
// Block = 256 threads = 16x16 pooled outputs (32x32 pre-pool), CO_BLK=8.
// ---------------------------------------------------------------------------
template <int CIN, int CI_BLK, int CO_BLK>
__launch_bounds__(256)
__global__ void conv_relu_pool_pipe(const float* __restrict__ in,
                                    const float* __restrict__ wgt,
                                    const float* __restrict__ bias,
                                    float* __restrict__ out,
                                    int Hin, int Win, int Cout) {
    constexpr int SPATIAL = 34 * 34;               // 1156
    constexpr int SSLOT = (SPATIAL + 255) / 256;   // 5
    constexpr int NW = CI_BLK * 9 * CO_BLK;        // weights per chunk
    constexpr int NCHUNK = CIN / CI_BLK;
    const int Hp = Hin >> 1, Wp = Win >> 1;
    const int coChunks = Cout / CO_BLK;
    const int b  = blockIdx.z / coChunks;
    const int cz = blockIdx.z % coChunks;
    const int tid = threadIdx.x;
    const int tx = tid & 15, ty = tid >> 4;
    const int px = (blockIdx.x << 4) + tx;
    const int py = (blockIdx.y << 4) + ty;
    const int iy0 = (blockIdx.y << 5) - 1;
    const int ix0 = (blockIdx.x << 5) - 1;

    __shared__ float  s_in[2][CI_BLK * SPATIAL];
    __shared__ double s_w[2][NW];

    int soff[SSLOT];
#pragma unroll
    for (int s = 0; s < SSLOT; ++s) {
        const int cell = tid + s * 256;
        int g = -1;
        if (cell < SPATIAL) {
            const int ly = cell / 34, lx = cell - ly * 34;
            const int iy = iy0 + ly, ix = ix0 + lx;
            if ((unsigned)iy < (unsigned)Hin && (unsigned)ix < (unsigned)Win)
                g = iy * Win + ix;
        }
        soff[s] = g;
    }
    int wg = -1;
    if (tid < NW) {
        const int co   = tid & (CO_BLK - 1);
        const int rest = tid / CO_BLK;
        const int k    = rest % 9;
        const int ci   = rest / 9;
        wg = ((cz * CO_BLK + co) * CIN + ci) * 9 + k;
    }
    const size_t HW = (size_t)Hin * Win;
    const float* in_b = in + (size_t)b * CIN * HW;

    double acc[CO_BLK][4];
#pragma unroll
    for (int co = 0; co < CO_BLK; ++co)
#pragma unroll
        for (int p = 0; p < 4; ++p) acc[co][p] = 0.0;

    float rin[CI_BLK][SSLOT];
    float rw = 0.f;

#pragma unroll
    for (int ci = 0; ci < CI_BLK; ++ci) {
        const float* src = in_b + ci * HW;
#pragma unroll
        for (int s = 0; s < SSLOT; ++s) {
            const int cell = tid + s * 256;
            float v = 0.f;
            if (cell < SPATIAL) { const int g = soff[s]; if (g >= 0) v = src[g]; }
            rin[ci][s] = v;
        }
    }
    if (tid < NW) rw = wgt[wg];
#pragma unroll
    for (int ci = 0; ci < CI_BLK; ++ci)
#pragma unroll
        for (int s = 0; s < SSLOT; ++s) {
            const int cell = tid + s * 256;
            if (cell < SPATIAL) s_in[0][ci * SPATIAL + cell] = rin[ci][s];
        }
    if (tid < NW) s_w[0][tid] = (double)rw;
    __syncthreads();

    for (int c = 0; c < NCHUNK; ++c) {
        const int buf = c & 1;
        if (c + 1 < NCHUNK) {
            const int c0n = (c + 1) * CI_BLK;
#pragma unroll
            for (int ci = 0; ci < CI_BLK; ++ci) {
                const float* src = in_b + (c0n + ci) * HW;
#pragma unroll
                for (int s = 0; s < SSLOT; ++s) {
                    const int cell = tid + s * 256;
                    float v = 0.f;
                    if (cell < SPATIAL) { const int g = soff[s]; if (g >= 0) v = src[g]; }
                    rin[ci][s] = v;
                }
            }
            if (tid < NW) rw = wgt[wg + c0n * 9];
        }
#pragma unroll 1
        for (int ci = 0; ci < CI_BLK; ++ci) {
            const float* tile = &s_in[buf][ci * SPATIAL];
            double win[4][4];
#pragma unroll
            for (int iy = 0; iy < 4; ++iy) {
                float2 r0 = *(const float2*)&tile[(2 * ty + iy) * 34 + 2 * tx];
                float2 r1 = *(const float2*)&tile[(2 * ty + iy) * 34 + 2 * tx + 2];
                win[iy][0] = (double)r0.x; win[iy][1] = (double)r0.y;
                win[iy][2] = (double)r1.x; win[iy][3] = (double)r1.y;
            }
#pragma unroll
            for (int k = 0; k < 9; ++k) {
                const int ky = k / 3, kx = k % 3;
                const double* wp = &s_w[buf][(ci * 9 + k) * CO_BLK];
                double w[CO_BLK];
#pragma unroll
                for (int co = 0; co < CO_BLK; ++co) w[co] = wp[co];
#pragma unroll
                for (int p = 0; p < 4; ++p) {
                    const double v = win[(p >> 1) + ky][(p & 1) + kx];
#pragma unroll
                    for (int co = 0; co < CO_BLK; ++co)
                        acc[co][p] = fma(v, w[co], acc[co][p]);
                }
            }
        }
        if (c + 1 < NCHUNK) {
#pragma unroll
            for (int ci = 0; ci < CI_BLK; ++ci)
#pragma unroll
                for (int s = 0; s < SSLOT; ++s) {
                    const int cell = tid + s * 256;
                    if (cell < SPATIAL) s_in[buf ^ 1][ci * SPATIAL + cell] = rin[ci][s];
                }
            if (tid < NW) s_w[buf ^ 1][tid] = (double)rw;
            __syncthreads();
        }
    }

#pragma unroll
    for (int co = 0; co < CO_BLK; ++co) {
        const double bd = (double)bias[cz * CO_BLK + co];
        const float e0 = fmaxf((float)(acc[co][0] + bd), 0.f);
        const float e1 = fmaxf((float)(acc[co][1] + bd), 0.f);
        const float e2 = fmaxf((float)(acc[co][2] + bd), 0.f);
        const float e3 = fmaxf((float)(acc[co][3] + bd), 0.f);
        out[((size_t)(b * Cout + cz * CO_BLK + co) * Hp + py) * Wp + px] =
            fmaxf(fmaxf(e0, e1), fmaxf(e2, e3));
    }
}

// ---------------------------------------------------------------------------
// L2-L4: implicit-GEMM conv via v_mfma_f64_16x16x4 (R21: 16-ci rounds,
// async input staging). Block = 256 thr = 4 waves; tile = 32x8 x 32 cout.
// Layouts (CK xdlops, f64 group_size=1):
//   A lane l -> A[i=l&15][k=l>>4];  B lane l -> B[k=l>>4][j=l&15];
//   D lane l reg r -> D[row = 4*r + (l>>4)][col = l&15]   (REGISTER-major)
// Pooling: vertical intra-thread (m pairs), horizontal via __shfl_xor(16).
// LDS: in f32 2x16x344 + w f32 2x16x296 = 81920 B exactly (2 blocks/CU).
// Input staging: global_load_lds (no dest regs -> no spill risk); halo
// zeros pre-filled once in both buffers, edge lanes skip via exec mask.
// Slot map: slot0 = cell tid, slot1 = cell 212+tid (tid<128; overlap
// 212-255 double-writes identical data — benign, R16-verified).
// ---------------------------------------------------------------------------
template <int CIN>
__launch_bounds__(256, 2)
__global__ void conv_mfma_f64(const float* __restrict__ in,
                              const float* __restrict__ wgt,
                              const float* __restrict__ bias,
                              float* __restrict__ out,
                              int Hin, int Win, int Cout) {
    constexpr int TW = 34;               // halo tile width  (32 + 2)
    constexpr int CELLS = 34 * 10;       // halo tile cells = 340
    constexpr int CH = 344;              // per-ci input stride (f32, ==24 mod 32)
    constexpr int CI_CHUNK = 16;
    constexpr int NCHUNK = CIN / CI_CHUNK;
    constexpr int WST = 296;             // per-ci weight stride (f32, ==8 mod 32)
    constexpr int NWS = CI_CHUNK * 9 * 32 / 256;   // 18 weight slots

    const int Hp = Hin >> 1, Wp = Win >> 1;
    const int coChunks = Cout >> 5;
    const int b   = blockIdx.z / coChunks;
    const int cob = blockIdx.z % coChunks;
    const int tid = threadIdx.x;
    const int wv  = tid >> 6;
    const int l15 = tid & 15;
    const int l4  = (tid >> 4) & 3;
    const int wb  = tid & 192;           // wave-uniform base (tid & ~63)
    const int x0 = blockIdx.x << 5;      // pre-pool tile origin x (32 wide)
    const int y0 = blockIdx.y << 3;      // pre-pool tile origin y (8 tall)

    __shared__ float s_in[2][CI_CHUNK * CH];
    __shared__ float s_w[2][CI_CHUNK * WST];

    // ---- staging geometry: slot0 = cell tid (all), slot1 = cell 212+tid
    // (tid<128; cells 212..339, overlap 212..255 rewrites identical data).
    int soff[2];
#pragma unroll
    for (int s = 0; s < 2; ++s) {
        const int cell = (s == 0) ? tid : (212 + tid);
        int g = -1;
        if (s == 0 || tid < 128) {
            const int ly = cell / TW, lx = cell - ly * TW;
            const int iy = y0 - 1 + ly, ix = x0 - 1 + lx;
            if ((unsigned)iy < (unsigned)Hin && (unsigned)ix < (unsigned)Win)
                g = iy * Win + ix;
        }
        soff[s] = g;
    }
    // Weight slots: idx = s*256+tid (s<18) covers the 4608 chunk weights.
    // co_l = tid&31; r = s*8 + (tid>>5) in 0..143; tap = r%9, ci = r/9.
    const int co_l = tid & 31;
    const int r8   = tid >> 5;
    const int wbase = (cob * 32 + co_l) * CIN * 9;

    const size_t HW = (size_t)Hin * Win;
    const float* in_b = in + (size_t)b * CIN * HW;

    // ---- per-wave mfma read bases (f32 element indices) ----
    int abase[4];
#pragma unroll
    for (int m = 0; m < 4; ++m) {
        const int dy = m >> 1, xh = m & 1;
        abase[m] = l4 * CH + (2 * wv + dy) * TW + xh * 16 + l15;
    }
    const int bbase0 = l4 * WST + l15;
    const int bbase1 = l4 * WST + 16 + l15;

    f64x4 acc[4][2];
#pragma unroll
    for (int m = 0; m < 4; ++m)
#pragma unroll
        for (int n = 0; n < 2; ++n)
#pragma unroll
            for (int j = 0; j < 4; ++j) acc[m][n][j] = 0.0;

    float rwt[NWS];

    // ---- prologue ----
    // Zero the chunk-invariant halo slots in BOTH buffers (edge lanes skip
    // their async copy via exec mask; these zeros persist).
#pragma unroll
    for (int s = 0; s < 2; ++s) {
        const int cell = (s == 0) ? tid : (212 + tid);
        if ((s == 0 || tid < 128) && soff[s] < 0) {
#pragma unroll
            for (int ci = 0; ci < CI_CHUNK; ++ci) {
                s_in[0][ci * CH + cell] = 0.f;
                s_in[1][ci * CH + cell] = 0.f;
            }
        }
    }
    // Stage chunk 0 (async) + weights chunk 0.
#pragma unroll
    for (int ci = 0; ci < CI_CHUNK; ++ci) {
        const float* src = in_b + (size_t)ci * HW;
        if (soff[0] >= 0)
            __builtin_amdgcn_global_load_lds(
                (const __attribute__((address_space(1))) void*)(src + soff[0]),
                (__attribute__((address_space(3))) void*)&s_in[0][ci * CH + wb],
                4, 0, 0);
        if (tid < 128 && soff[1] >= 0)
            __builtin_amdgcn_global_load_lds(
                (const __attribute__((address_space(1))) void*)(src + soff[1]),
                (__attribute__((address_space(3))) void*)&s_in[0][ci * CH + 212 + wb],
                4, 0, 0);
    }
#pragma unroll
    for (int s = 0; s < NWS; ++s) {
        const int r = s * 8 + r8;
        const int tap = r % 9, ci = r / 9;
        rwt[s] = wgt[wbase + ci * 9 + tap];
    }
#pragma unroll
    for (int s = 0; s < NWS; ++s) {
        const int r = s * 8 + r8;
        const int tap = r % 9, ci = r / 9;
        s_w[0][ci * WST + tap * 32 + co_l] = rwt[s];
    }
    __syncthreads();   // drains vmcnt(0): chunk 0 resident

    // kk = tap*2 + g within a sub-chunk h (ci4-group = 2h + g).
#define R21_KA(kk) ((((kk)&1) * 4 * CH) + ((((kk)>>1) / 3) * TW) + (((kk)>>1) % 3))
#define R21_KB(kk) ((((kk)&1) * 4 * WST) + (((kk)>>1) * 32))

#pragma unroll 1
    for (int c = 0; c < NCHUNK; ++c) {
        const int buf = c & 1;
        // ---- issue next round's async input copies (unsinkable) ----
        if (c + 1 < NCHUNK) {
            const int c0n = (c + 1) * CI_CHUNK;
#pragma unroll
            for (int ci = 0; ci < CI_CHUNK; ++ci) {
                const float* src = in_b + (size_t)(c0n + ci) * HW;
                if (soff[0] >= 0)
                    __builtin_amdgcn_global_load_lds(
                        (const __attribute__((address_space(1))) void*)(src + soff[0]),
                        (__attribute__((address_space(3))) void*)&s_in[buf ^ 1][ci * CH + wb],
                        4, 0, 0);
                if (tid < 128 && soff[1] >= 0)
                    __builtin_amdgcn_global_load_lds(
                        (const __attribute__((address_space(1))) void*)(src + soff[1]),
                        (__attribute__((address_space(3))) void*)&s_in[buf ^ 1][ci * CH + 212 + wb],
                        4, 0, 0);
            }
#pragma unroll
            for (int s = 0; s < NWS; ++s) {
                const int r = s * 8 + r8;
                const int tap = r % 9, ci = r / 9;
                rwt[s] = wgt[wbase + (c0n + ci) * 9 + tap];
            }
        }
        // ---- compute: 2 sub-chunks x 18 kk-iters x 8 mfma = 288 mfma ----
#pragma unroll
        for (int h = 0; h < 2; ++h) {
            const float* ti = &s_in[buf][h * 8 * CH];
            const float* tw = &s_w[buf][h * 8 * WST];
            double A0, A1, A2, A3, B0, B1;
            B0 = (double)tw[bbase0 + R21_KB(0)];
            B1 = (double)tw[bbase1 + R21_KB(0)];
            A0 = (double)ti[abase[0] + R21_KA(0)];
            A1 = (double)ti[abase[1] + R21_KA(0)];
            A2 = (double)ti[abase[2] + R21_KA(0)];
            A3 = (double)ti[abase[3] + R21_KA(0)];
#pragma unroll
            for (int kk = 0; kk < 18; ++kk) {
                double nA0, nA1, nA2, nA3, nB0, nB1;
                if (kk + 1 < 18) {
                    nB0 = (double)tw[bbase0 + R21_KB(kk + 1)];
                    nB1 = (double)tw[bbase1 + R21_KB(kk + 1)];
                    nA0 = (double)ti[abase[0] + R21_KA(kk + 1)];
                    nA1 = (double)ti[abase[1] + R21_KA(kk + 1)];
                    nA2 = (double)ti[abase[2] + R21_KA(kk + 1)];
                    nA3 = (double)ti[abase[3] + R21_KA(kk + 1)];
                }
                acc[0][0] = __builtin_amdgcn_mfma_f64_16x16x4f64(A0, B0, acc[0][0], 0, 0, 0);
                acc[0][1] = __builtin_amdgcn_mfma_f64_16x16x4f64(A0, B1, acc[0][1], 0, 0, 0);
                acc[1][0] = __builtin_amdgcn_mfma_f64_16x16x4f64(A1, B0, acc[1][0], 0, 0, 0);
                acc[1][1] = __builtin_amdgcn_mfma_f64_16x16x4f64(A1, B1, acc[1][1], 0, 0, 0);
                acc[2][0] = __builtin_amdgcn_mfma_f64_16x16x4f64(A2, B0, acc[2][0], 0, 0, 0);
                acc[2][1] = __builtin_amdgcn_mfma_f64_16x16x4f64(A2, B1, acc[2][1], 0, 0, 0);
                acc[3][0] = __builtin_amdgcn_mfma_f64_16x16x4f64(A3, B0, acc[3][0], 0, 0, 0);
                acc[3][1] = __builtin_amdgcn_mfma_f64_16x16x4f64(A3, B1, acc[3][1], 0, 0, 0);
                if (kk + 1 < 18) {
                    A0 = nA0; A1 = nA1; A2 = nA2; A3 = nA3;
                    B0 = nB0; B1 = nB1;
                }
            }
        }
        // ---- commit weights to the other buffer, one barrier ----
        if (c + 1 < NCHUNK) {
#pragma unroll
            for (int s = 0; s < NWS; ++s) {
                const int r = s * 8 + r8;
                const int tap = r % 9, ci = r / 9;
                s_w[buf ^ 1][ci * WST + tap * 32 + co_l] = rwt[s];
            }
            __syncthreads();   // vmcnt(0) drain: next round's inputs resident
        }
    }
#undef R21_KA
#undef R21_KB

    // ---- epilogue: bias (f64) -> relu (f32) -> 2x2 maxpool -> store.
    // Reg r of acc[m][n] holds pre-pool x = x0 + xh*16 + 4r + l4, y = y0+2wv+dy.
    // Vertical pool intra-thread (m pairs); horizontal partner x^1 = lane^16.
    const int yp = (y0 >> 1) + wv;
#pragma unroll
    for (int n = 0; n < 2; ++n) {
        const int co = cob * 32 + n * 16 + l15;
        const double bd = (double)bias[co];
        float* orow = out + (((size_t)b * Cout + co) * Hp + yp) * Wp;
#pragma unroll
        for (int xh = 0; xh < 2; ++xh) {
#pragma unroll
            for (int r = 0; r < 4; ++r) {
                const float e0 = fmaxf((float)(acc[xh][n][r]     + bd), 0.f);
                const float e1 = fmaxf((float)(acc[2 + xh][n][r] + bd), 0.f);
                float v = fmaxf(e0, e1);                 // vertical pool
                const float p = __shfl_xor(v, 16, 64);   // horizontal partner
                v = fmaxf(v, p);
                if ((l4 & 1) == 0) {
                    const int xp = (x0 >> 1) + xh * 8 + 2 * r + (l4 >> 1);
                    orow[xp] = v;
                }
            }
        }
    }
}

// ---------------------------------------------------------------------------
// Head 1x1 conv (256->5, f64) + decode (f64) -> boxes/scores. 32 blocks.
// ---------------------------------------------------------------------------
__launch_bounds__(256)
__global__ void head_decode_k(const float* __restrict__ x4,
                              const float* __restrict__ wh,
                              const float* __restrict__ bh,
                              float* __restrict__ boxes,
                              float* __restrict__ scores) {
    __shared__ float s_wh[5 * 256];
    const int tid = threadIdx.x;
#pragma unroll
    for (int i = 0; i < 5; ++i) s_wh[i * 256 + tid] = wh[i * 256 + tid];
    __syncthreads();

    const int idx  = blockIdx.x * 256 + tid;  // 0..8191
    const int b    = idx >> 10;
    const int cell = idx & 1023;
    const int gy = cell >> 5, gx = cell & 31;

    double a0 = (double)bh[0], a1 = (double)bh[1], a2 = (double)bh[2],
           a3 = (double)bh[3], a4 = (double)bh[4];
    const float* xp = x4 + b * 262144 + cell;
    for (int ci = 0; ci < 256; ++ci) {
        const double v = (double)xp[ci << 10];
        a0 = fma(v, (double)s_wh[0 * 256 + ci], a0);
        a1 = fma(v, (double)s_wh[1 * 256 + ci], a1);
        a2 = fma(v, (double)s_wh[2 * 256 + ci], a2);
        a3 = fma(v, (double)s_wh[3 * 256 + ci], a3);
        a4 = fma(v, (double)s_wh[4 * 256 + ci], a4);
    }
    const double obj = 1.0 / (1.0 + exp(-a0));
    const double txs = 1.0 / (1.0 + exp(-a1));
    const double tys = 1.0 / (1.0 + exp(-a2));
    const double bw  = exp(a3) * 16.0;
    const double bhh = exp(a4) * 16.0;
    const double cx  = gx * 16.0 + txs * 16.0;
    const double cy  = gy * 16.0 + tys * 16.0;
    float* bp = boxes + idx * 4;
    bp[0] = (float)fmin(fmax(cx - bw * 0.5, 0.0), 511.0);
    bp[1] = (float)fmin(fmax(cy - bhh * 0.5, 0.0), 511.0);
    bp[2] = (float)fmin(fmax(cx + bw * 0.5, 0.0), 511.0);
    bp[3] = (float)fmin(fmax(cy + bhh * 0.5, 0.0), 511.0);
    scores[idx] = (float)obj;
}

// ---------------------------------------------------------------------------
// Per-batch top-200 (bitonic, lax.top_k tie semantics) + greedy NMS + output.
// ---------------------------------------------------------------------------
__launch_bounds__(256)
__global__ void topk_nms_k(const float* __restrict__ boxes,
                           const float* __restrict__ scores,
                           float* __restrict__ out5,
                           float* __restrict__ keep_out) {
    const int b = blockIdx.x, tid = threadIdx.x;
    __shared__ unsigned long long key[1024];
    __shared__ float bx1[TOPK_N], by1[TOPK_N], bx2[TOPK_N], by2[TOPK_N];
    __shared__ float sv[TOPK_N], ar[TOPK_N];
    __shared__ int   kp[TOPK_N];

    for (int i = tid; i < 1024; i += 256) {
        float s = scores[b * 1024 + i];
        float m = (s >= 0.01f) ? s : -1.0f;
        unsigned u = __float_as_uint(m);
        u = (u & 0x80000000u) ? ~u : (u | 0x80000000u);
        key[i] = ((unsigned long long)u << 32) | (unsigned)(1023 - i);
    }
    __syncthreads();

    for (int k = 2; k <= 1024; k <<= 1) {
        for (int j = k >> 1; j > 0; j >>= 1) {
            for (int i = tid; i < 1024; i += 256) {
                int l = i ^ j;
                if (l > i) {
                    unsigned long long a = key[i], c = key[l];
                    bool desc = ((i & k) == 0);
                    bool sw = desc ? (a < c) : (a > c);
                    if (sw) { key[i] = c; key[l] = a; }
                }
            }
            __syncthreads();
        }
    }

    for (int i = tid; i < TOPK_N; i += 256) {
        unsigned long long kk = key[i];
        unsigned u = (unsigned)(kk >> 32);
        unsigned bits = (u & 0x80000000u) ? (u & 0x7FFFFFFFu) : ~u;
        float s = __uint_as_float(bits);
        int src = 1023 - (int)(kk & 0xFFFFFFFFu);
        const float4 bb = *(const float4*)(boxes + (b * 1024 + src) * 4);
        bx1[i] = bb.x; by1[i] = bb.y; bx2[i] = bb.z; by2[i] = bb.w;
        sv[i] = s;
        ar[i] = (bb.z - bb.x) * (bb.w - bb.y);
        kp[i] = (s >= 0.01f) ? 1 : 0;
    }
    __syncthreads();

    for (int i = 0; i < TOPK_N; ++i) {
        if (kp[i]) {
            const float X1 = bx1[i], Y1 = by1[i], X2 = bx2[i], Y2 = by2[i], A = ar[i];
            for (int j = tid; j < TOPK_N; j += 256) {
                if (j > i && kp[j]) {
                    float xx1 = fmaxf(X1, bx1[j]);
                    float yy1 = fmaxf(Y1, by1[j]);
                    float xx2 = fminf(X2, bx2[j]);
                    float yy2 = fminf(Y2, by2[j]);
                    float inter = fmaxf(xx2 - xx1, 0.f) * fmaxf(yy2 - yy1, 0.f);
                    float uni = A + ar[j] - inter;
                    float iou = inter / fmaxf(uni, 1e-6f);
                    if (iou > 0.5f) kp[j] = 0;
                }
            }
        }
        __syncthreads();
    }

    for (int i = tid; i < TOPK_N; i += 256) {
        float kf = kp[i] ? 1.f : 0.f;
        float s  = sv[i];
        float sc = (s >= 0.01f) ? s : 0.f;
        float* op = out5 + (b * TOPK_N + i) * 5;
        op[0] = bx1[i] * kf;
        op[1] = by1[i] * kf;
        op[2] = bx2[i] * kf;
        op[3] = by2[i] * kf;
        op[4] = sc * kf;
        keep_out[b * TOPK_N + i] = kf;
    }
}

extern "C" void kernel_launch(void* const* d_in, const int* in_sizes, int n_in,
                              void* d_out, int out_size, void* d_ws, size_t ws_size,
                              hipStream_t stream) {
    const float* images = (const float*)d_in[0];
    const float* w1 = (const float*)d_in[1];
    const float* b1 = (const float*)d_in[2];
    const float* w2 = (const float*)d_in[3];
    const float* b2 = (const float*)d_in[4];
    const float* w3 = (const float*)d_in[5];
    const float* b3 = (const float*)d_in[6];
    const float* w4 = (const float*)d_in[7];
    const float* b4 = (const float*)d_in[8];
    const float* wh = (const float*)d_in[9];
    const float* bh = (const float*)d_in[10];
    float* out = (float*)d_out;

    float* A    = (float*)d_ws;          // x1 [8,32,256,256] -> x3 [8,128,64,64]
    float* Bbuf = A + 16777216;          // x2 [8,64,128,128] -> x4 [8,256,32,32]
    float* boxes  = A + 8388608;         // dead x1 space: 32768 floats
    float* scores = A + 8388608 + 32768; //  8192 floats

    // L1: 3->32, 512x512 -> 256x256. VALU-f64 template (CIN=3 not mfma-shaped).
    conv_relu_pool_pipe<3, 3, 8><<<dim3(16, 16, 8 * 4), 256, 0, stream>>>(
        images, w1, b1, A, 512, 512, 32);
    // L2: 32->64, 256x256 in. MFMA-f64: grid (Wpre/32, Hpre/8, B*Cout/32).
    conv_mfma_f64<32><<<dim3(8, 32, 8 * 2), 256, 0, stream>>>(
        A, w2, b2, Bbuf, 256, 256, 64);
    // L3: 64->128, 128x128 in.
    conv_mfma_f64<64><<<dim3(4, 16, 8 * 4), 256, 0, stream>>>(
        Bbuf, w3, b3, A, 128, 128, 128);
    // L4: 128->256, 64x64 in.
    conv_mfma_f64<128><<<dim3(2, 8, 8 * 8), 256, 0, stream>>>(
        A, w4, b4, Bbuf, 64, 64, 256);
    // Head + decode: 32 blocks, coalesced
    head_decode_k<<<32, 256, 0, stream>>>(Bbuf, wh, bh, boxes, scores);
    // Top-k + NMS + output
    topk_nms_k<<<8, 256, 0, stream>>>(boxes, scores, out, out + 8 * TOPK_N * 5);
}